// Round 1
// baseline (2506.705 us; speedup 1.0000x reference)
//
#include <hip/hip_runtime.h>

// GALA graph autoencoder on MI355X.
// N=100000 nodes, E=600000 edges, T=128 features, dims 128->64->32->16->32->64->128.
// Key identity: prop(A@W) == prop(A)@W, so propagate at the smaller feature dim:
//   encoder (128->64 etc): GEMM first, then propagate at dout
//   decoder (16->32 etc):  propagate at din first, then GEMM
// Propagation = self-loop init + atomic scatter over edges.

static inline int ceil_div(int a, int b) { return (a + b - 1) / b; }

// ---------------- degree / norm precompute ----------------

__global__ void deg_kernel(const int* __restrict__ col, int* __restrict__ deg, int E) {
    int e = blockIdx.x * blockDim.x + threadIdx.x;
    if (e < E) atomicAdd(&deg[col[e]], 1);
}

__global__ void dinv_kernel(const int* __restrict__ deg, float* __restrict__ dinv_s,
                            float* __restrict__ dinv_h, int n) {
    int i = blockIdx.x * blockDim.x + threadIdx.x;
    if (i < n) {
        float d = (float)deg[i];
        dinv_s[i] = rsqrtf(d + 1.0f);  // smooth: deg = indeg + 1 (self loop w=1)
        dinv_h[i] = rsqrtf(d + 2.0f);  // sharp:  deg = indeg + 2 (self loop w=2)
    }
}

__global__ void ew_kernel(const int* __restrict__ row, const int* __restrict__ col,
                          const float* __restrict__ dinv_s, const float* __restrict__ dinv_h,
                          float* __restrict__ sw, float* __restrict__ hw, int E) {
    int e = blockIdx.x * blockDim.x + threadIdx.x;
    if (e < E) {
        int r = row[e], c = col[e];
        sw[e] = dinv_s[r] * dinv_s[c];
        hw[e] = -dinv_h[r] * dinv_h[c];
    }
}

// ---------------- small GEMM with W in LDS ----------------
// out[n,dout] = f(A[n,din]) @ W[din,dout] (+bias) (relu)
// block = 256 threads, each thread owns one (row, d) output.

template <bool RELU_IN, bool ADD_BIAS, bool RELU_OUT>
__global__ void gemm_kernel(const float* __restrict__ A, const float* __restrict__ W,
                            const float* __restrict__ bias, float* __restrict__ out,
                            int n, int din, int dout) {
    extern __shared__ float Wl[];
    for (int i = threadIdx.x; i < din * dout; i += blockDim.x) Wl[i] = W[i];
    __syncthreads();
    int rpb = blockDim.x / dout;
    int d = threadIdx.x % dout;
    int r = threadIdx.x / dout;
    int rowi = blockIdx.x * rpb + r;
    if (rowi >= n) return;
    const float* a = A + (size_t)rowi * din;
    float acc = 0.0f;
#pragma unroll 4
    for (int k = 0; k < din; ++k) {
        float av = a[k];
        if (RELU_IN) av = fmaxf(av, 0.0f);
        acc = fmaf(av, Wl[k * dout + d], acc);
    }
    if (ADD_BIAS) acc += bias[d];
    if (RELU_OUT) acc = fmaxf(acc, 0.0f);
    out[(size_t)rowi * dout + d] = acc;
}

// ---------------- propagation: self-loop init ----------------
// out[node,d] = selfcoef*dinv[node]^2 * f(h[node,d]) (+ bias[d])

template <bool RELU_IN, bool ADD_BIAS>
__global__ void prop_init_kernel(const float* __restrict__ h, const float* __restrict__ dinv,
                                 float selfcoef, const float* __restrict__ bias,
                                 float* __restrict__ out, int n, int dout, int dq_shift) {
    int idx = blockIdx.x * blockDim.x + threadIdx.x;
    int dq = 1 << dq_shift;           // dout/4
    int node = idx >> dq_shift;
    if (node >= n) return;
    int d4 = (idx & (dq - 1)) << 2;
    float w = dinv[node];
    w = selfcoef * w * w;
    float4 h4 = *(const float4*)(h + (size_t)node * dout + d4);
    if (RELU_IN) {
        h4.x = fmaxf(h4.x, 0.0f); h4.y = fmaxf(h4.y, 0.0f);
        h4.z = fmaxf(h4.z, 0.0f); h4.w = fmaxf(h4.w, 0.0f);
    }
    float4 o;
    o.x = w * h4.x; o.y = w * h4.y; o.z = w * h4.z; o.w = w * h4.w;
    if (ADD_BIAS) {
        o.x += bias[d4]; o.y += bias[d4 + 1]; o.z += bias[d4 + 2]; o.w += bias[d4 + 3];
    }
    *(float4*)(out + (size_t)node * dout + d4) = o;
}

// ---------------- propagation: edge scatter (atomic) ----------------
// out[col[e],d] += ew[e] * f(h[row[e],d])

template <bool RELU_IN>
__global__ void scatter_kernel(const float* __restrict__ h, const int* __restrict__ row,
                               const int* __restrict__ col, const float* __restrict__ ew,
                               float* __restrict__ out, int E, int dout, int dq_shift) {
    int idx = blockIdx.x * blockDim.x + threadIdx.x;
    int dq = 1 << dq_shift;           // dout/4
    int e = idx >> dq_shift;
    if (e >= E) return;
    int d4 = (idx & (dq - 1)) << 2;
    int r = row[e], c = col[e];
    float w = ew[e];
    float4 h4 = *(const float4*)(h + (size_t)r * dout + d4);
    if (RELU_IN) {
        h4.x = fmaxf(h4.x, 0.0f); h4.y = fmaxf(h4.y, 0.0f);
        h4.z = fmaxf(h4.z, 0.0f); h4.w = fmaxf(h4.w, 0.0f);
    }
    float* o = out + (size_t)c * dout + d4;
    atomicAdd(o + 0, w * h4.x);
    atomicAdd(o + 1, w * h4.y);
    atomicAdd(o + 2, w * h4.z);
    atomicAdd(o + 3, w * h4.w);
}

// ---------------- host orchestration ----------------

static int dq_shift_of(int dout) {
    // dout/4 as a power-of-two shift: dout in {16,32,64,128} -> dq in {4,8,16,32}
    int dq = dout >> 2, s = 0;
    while ((1 << s) < dq) ++s;
    return s;
}

extern "C" void kernel_launch(void* const* d_in, const int* in_sizes, int n_in,
                              void* d_out, int out_size, void* d_ws, size_t ws_size,
                              hipStream_t stream) {
    const int T = 128;
    const int n = in_sizes[0] / T;        // 100000
    const int E = in_sizes[1] / 2;        // 600000

    const float* x   = (const float*)d_in[0];
    const int* eidx  = (const int*)d_in[1];
    const int* row   = eidx;
    const int* col   = eidx + E;
    const float* We1 = (const float*)d_in[2];
    const float* be1 = (const float*)d_in[3];
    const float* We2 = (const float*)d_in[4];
    const float* be2 = (const float*)d_in[5];
    const float* We3 = (const float*)d_in[6];
    const float* be3 = (const float*)d_in[7];
    const float* Wd1 = (const float*)d_in[8];
    const float* bd1 = (const float*)d_in[9];
    const float* Wd2 = (const float*)d_in[10];
    const float* bd2 = (const float*)d_in[11];
    const float* Wd3 = (const float*)d_in[12];
    const float* bd3 = (const float*)d_in[13];
    float* out = (float*)d_out;

    // workspace layout (all 16B aligned)
    char* base = (char*)d_ws;
    int*   deg    = (int*)base;              base += (size_t)n * 4;
    float* dinv_s = (float*)base;            base += (size_t)n * 4;
    float* dinv_h = (float*)base;            base += (size_t)n * 4;
    float* sw     = (float*)base;            base += (size_t)E * 4;
    float* hw     = (float*)base;            base += (size_t)E * 4;
    float* bufA   = (float*)base;            base += (size_t)n * 64 * 4;
    float* bufB   = (float*)base;            base += (size_t)n * 64 * 4;
    (void)ws_size;

    const int BLK = 256;

    // --- norm precompute ---
    hipMemsetAsync(deg, 0, (size_t)n * 4, stream);
    deg_kernel<<<ceil_div(E, BLK), BLK, 0, stream>>>(col, deg, E);
    dinv_kernel<<<ceil_div(n, BLK), BLK, 0, stream>>>(deg, dinv_s, dinv_h, n);
    ew_kernel<<<ceil_div(E, BLK), BLK, 0, stream>>>(row, col, dinv_s, dinv_h, sw, hw, E);

    auto gemm_grid = [&](int dout) { return ceil_div(n, BLK / dout); };
    auto init_grid = [&](int dout) { return ceil_div(n * (dout >> 2), BLK); };
    auto scat_grid = [&](int dout) { return ceil_div(E * (dout >> 2), BLK); };

    // ================= encoder (smooth): GEMM then propagate =================
    // L1: x(128) @ We1 -> H(64); prop + be1 (relu deferred to consumer load)
    gemm_kernel<false, false, false><<<gemm_grid(64), BLK, 128 * 64 * 4, stream>>>(
        x, We1, nullptr, bufA, n, 128, 64);
    prop_init_kernel<false, true><<<init_grid(64), BLK, 0, stream>>>(
        bufA, dinv_s, 1.0f, be1, bufB, n, 64, dq_shift_of(64));
    scatter_kernel<false><<<scat_grid(64), BLK, 0, stream>>>(
        bufA, row, col, sw, bufB, E, 64, dq_shift_of(64));

    // L2: relu(P1)(64) @ We2 -> H(32); prop + be2
    gemm_kernel<true, false, false><<<gemm_grid(32), BLK, 64 * 32 * 4, stream>>>(
        bufB, We2, nullptr, bufA, n, 64, 32);
    prop_init_kernel<false, true><<<init_grid(32), BLK, 0, stream>>>(
        bufA, dinv_s, 1.0f, be2, bufB, n, 32, dq_shift_of(32));
    scatter_kernel<false><<<scat_grid(32), BLK, 0, stream>>>(
        bufA, row, col, sw, bufB, E, 32, dq_shift_of(32));

    // L3: relu(P2)(32) @ We3 -> H(16); prop + be3 -> Z (pre-relu) in bufB
    gemm_kernel<true, false, false><<<gemm_grid(16), BLK, 32 * 16 * 4, stream>>>(
        bufB, We3, nullptr, bufA, n, 32, 16);
    prop_init_kernel<false, true><<<init_grid(16), BLK, 0, stream>>>(
        bufA, dinv_s, 1.0f, be3, bufB, n, 16, dq_shift_of(16));
    scatter_kernel<false><<<scat_grid(16), BLK, 0, stream>>>(
        bufA, row, col, sw, bufB, E, 16, dq_shift_of(16));

    // ================= decoder (sharp): propagate then GEMM =================
    // L4: Q = prop(relu(Z))(16); Q @ Wd1 + bd1, relu
    prop_init_kernel<true, false><<<init_grid(16), BLK, 0, stream>>>(
        bufB, dinv_h, 2.0f, nullptr, bufA, n, 16, dq_shift_of(16));
    scatter_kernel<true><<<scat_grid(16), BLK, 0, stream>>>(
        bufB, row, col, hw, bufA, E, 16, dq_shift_of(16));
    gemm_kernel<false, true, true><<<gemm_grid(32), BLK, 16 * 32 * 4, stream>>>(
        bufA, Wd1, bd1, bufB, n, 16, 32);

    // L5: Q = prop(h)(32); Q @ Wd2 + bd2, relu
    prop_init_kernel<false, false><<<init_grid(32), BLK, 0, stream>>>(
        bufB, dinv_h, 2.0f, nullptr, bufA, n, 32, dq_shift_of(32));
    scatter_kernel<false><<<scat_grid(32), BLK, 0, stream>>>(
        bufB, row, col, hw, bufA, E, 32, dq_shift_of(32));
    gemm_kernel<false, true, true><<<gemm_grid(64), BLK, 32 * 64 * 4, stream>>>(
        bufA, Wd2, bd2, bufB, n, 32, 64);

    // L6: Q = prop(h)(64); Q @ Wd3 + bd3 -> d_out (no relu)
    prop_init_kernel<false, false><<<init_grid(64), BLK, 0, stream>>>(
        bufB, dinv_h, 2.0f, nullptr, bufA, n, 64, dq_shift_of(64));
    scatter_kernel<false><<<scat_grid(64), BLK, 0, stream>>>(
        bufB, row, col, hw, bufA, E, 64, dq_shift_of(64));
    gemm_kernel<false, true, false><<<gemm_grid(128), BLK, 64 * 128 * 4, stream>>>(
        bufA, Wd3, bd3, out, n, 64, 128);
}

// Round 2
// 984.299 us; speedup vs baseline: 2.5467x; 2.5467x over previous
//
#include <hip/hip_runtime.h>

// GALA graph autoencoder on MI355X — round 2: scatter->gather via CSR.
// N=100000 nodes, E=600000 edges, dims 128->64->32->16->32->64->128.
// prop(A@W) == prop(A)@W, so propagate at the smaller feature dim.
// Propagation = register-accumulated gather over CSR in-edges (no float atomics),
// with self-loop, bias, and input-ReLU fused.

static inline int ceil_div(int a, int b) { return (a + b - 1) / b; }

#define SCAN_BLK 256

// ---------------- degree / norm precompute ----------------

__global__ void deg_kernel(const int* __restrict__ col, int* __restrict__ deg, int E) {
    int e = blockIdx.x * blockDim.x + threadIdx.x;
    if (e < E) atomicAdd(&deg[col[e]], 1);
}

__global__ void dinv_kernel(const int* __restrict__ deg, float* __restrict__ dinv_s,
                            float* __restrict__ dinv_h, int n) {
    int i = blockIdx.x * blockDim.x + threadIdx.x;
    if (i < n) {
        float d = (float)deg[i];
        dinv_s[i] = rsqrtf(d + 1.0f);  // smooth: deg = indeg + 1 (self loop w=1)
        dinv_h[i] = rsqrtf(d + 2.0f);  // sharp:  deg = indeg + 2 (self loop w=2)
    }
}

// ---------------- CSR build: block scan of degrees ----------------

__global__ void blk_reduce_kernel(const int* __restrict__ deg, int* __restrict__ bsum, int n) {
    __shared__ int s[SCAN_BLK];
    int i = blockIdx.x * SCAN_BLK + threadIdx.x;
    s[threadIdx.x] = (i < n) ? deg[i] : 0;
    __syncthreads();
    for (int st = SCAN_BLK / 2; st > 0; st >>= 1) {
        if (threadIdx.x < st) s[threadIdx.x] += s[threadIdx.x + st];
        __syncthreads();
    }
    if (threadIdx.x == 0) bsum[blockIdx.x] = s[0];
}

// single block of 1024 threads; nb <= 1024. bsum -> exclusive prefix in place.
__global__ void bsum_scan_kernel(int* bsum, int nb) {
    __shared__ int s[1024];
    int t = threadIdx.x;
    int v0 = (t < nb) ? bsum[t] : 0;
    s[t] = v0;
    __syncthreads();
    for (int st = 1; st < 1024; st <<= 1) {
        int add = (t >= st) ? s[t - st] : 0;
        __syncthreads();
        s[t] += add;
        __syncthreads();
    }
    if (t < nb) bsum[t] = s[t] - v0;  // exclusive
}

// offs[i] = bpre[blk] + exclusive_scan_within_block(deg)[i], covers i in [0, n]
__global__ void offs_kernel(const int* __restrict__ deg, const int* __restrict__ bpre,
                            int* __restrict__ offs, int n) {
    __shared__ int s[SCAN_BLK];
    int i = blockIdx.x * SCAN_BLK + threadIdx.x;
    int t = threadIdx.x;
    int v0 = (i < n) ? deg[i] : 0;
    s[t] = v0;
    __syncthreads();
    for (int st = 1; st < SCAN_BLK; st <<= 1) {
        int add = (t >= st) ? s[t - st] : 0;
        __syncthreads();
        s[t] += add;
        __syncthreads();
    }
    if (i <= n) offs[i] = bpre[blockIdx.x] + s[t] - v0;
}

// permute edges into CSR order keyed by col; store src index + both weight sets
__global__ void csr_fill_kernel(const int* __restrict__ row, const int* __restrict__ col,
                                const float* __restrict__ dinv_s, const float* __restrict__ dinv_h,
                                int* __restrict__ cursor, int* __restrict__ src,
                                float* __restrict__ swp, float* __restrict__ hwp, int E) {
    int e = blockIdx.x * blockDim.x + threadIdx.x;
    if (e >= E) return;
    int r = row[e], c = col[e];
    int p = atomicAdd(&cursor[c], 1);
    src[p] = r;
    swp[p] = dinv_s[r] * dinv_s[c];
    hwp[p] = -dinv_h[r] * dinv_h[c];
}

// ---------------- small GEMM with W in LDS ----------------

template <bool RELU_IN, bool ADD_BIAS, bool RELU_OUT>
__global__ void gemm_kernel(const float* __restrict__ A, const float* __restrict__ W,
                            const float* __restrict__ bias, float* __restrict__ out,
                            int n, int din, int dout) {
    extern __shared__ float Wl[];
    for (int i = threadIdx.x; i < din * dout; i += blockDim.x) Wl[i] = W[i];
    __syncthreads();
    int rpb = blockDim.x / dout;
    int d = threadIdx.x % dout;
    int r = threadIdx.x / dout;
    int rowi = blockIdx.x * rpb + r;
    if (rowi >= n) return;
    const float* a = A + (size_t)rowi * din;
    float acc = 0.0f;
#pragma unroll 4
    for (int k = 0; k < din; ++k) {
        float av = a[k];
        if (RELU_IN) av = fmaxf(av, 0.0f);
        acc = fmaf(av, Wl[k * dout + d], acc);
    }
    if (ADD_BIAS) acc += bias[d];
    if (RELU_OUT) acc = fmaxf(acc, 0.0f);
    out[(size_t)rowi * dout + d] = acc;
}

// ---------------- propagation: fused CSR gather ----------------
// out[node, d4..d4+3] = selfcoef*dinv[node]^2 * f(h[node]) (+bias)
//                     + sum_e w[e] * f(h[src[e]])

template <bool RELU_IN, bool ADD_BIAS>
__global__ void gather_kernel(const float* __restrict__ h, const int* __restrict__ offs,
                              const int* __restrict__ src, const float* __restrict__ wp,
                              const float* __restrict__ dinv, float selfcoef,
                              const float* __restrict__ bias, float* __restrict__ out,
                              int n, int dout, int dq_shift) {
    int idx = blockIdx.x * blockDim.x + threadIdx.x;
    int dq = 1 << dq_shift;           // dout/4
    int node = idx >> dq_shift;
    if (node >= n) return;
    int d4 = (idx & (dq - 1)) << 2;

    float dv = dinv[node];
    float selfw = selfcoef * dv * dv;
    float4 h4 = *(const float4*)(h + (size_t)node * dout + d4);
    if (RELU_IN) {
        h4.x = fmaxf(h4.x, 0.0f); h4.y = fmaxf(h4.y, 0.0f);
        h4.z = fmaxf(h4.z, 0.0f); h4.w = fmaxf(h4.w, 0.0f);
    }
    float4 acc;
    acc.x = selfw * h4.x; acc.y = selfw * h4.y;
    acc.z = selfw * h4.z; acc.w = selfw * h4.w;
    if (ADD_BIAS) {
        acc.x += bias[d4]; acc.y += bias[d4 + 1];
        acc.z += bias[d4 + 2]; acc.w += bias[d4 + 3];
    }

    int s = offs[node], epos = offs[node + 1];
    for (int e = s; e < epos; ++e) {
        int r = src[e];
        float w = wp[e];
        float4 v = *(const float4*)(h + (size_t)r * dout + d4);
        if (RELU_IN) {
            v.x = fmaxf(v.x, 0.0f); v.y = fmaxf(v.y, 0.0f);
            v.z = fmaxf(v.z, 0.0f); v.w = fmaxf(v.w, 0.0f);
        }
        acc.x = fmaf(w, v.x, acc.x); acc.y = fmaf(w, v.y, acc.y);
        acc.z = fmaf(w, v.z, acc.z); acc.w = fmaf(w, v.w, acc.w);
    }
    *(float4*)(out + (size_t)node * dout + d4) = acc;
}

// ---------------- host orchestration ----------------

static int dq_shift_of(int dout) {
    int dq = dout >> 2, s = 0;
    while ((1 << s) < dq) ++s;
    return s;
}

extern "C" void kernel_launch(void* const* d_in, const int* in_sizes, int n_in,
                              void* d_out, int out_size, void* d_ws, size_t ws_size,
                              hipStream_t stream) {
    const int T = 128;
    const int n = in_sizes[0] / T;        // 100000
    const int E = in_sizes[1] / 2;        // 600000

    const float* x   = (const float*)d_in[0];
    const int* eidx  = (const int*)d_in[1];
    const int* row   = eidx;
    const int* col   = eidx + E;
    const float* We1 = (const float*)d_in[2];
    const float* be1 = (const float*)d_in[3];
    const float* We2 = (const float*)d_in[4];
    const float* be2 = (const float*)d_in[5];
    const float* We3 = (const float*)d_in[6];
    const float* be3 = (const float*)d_in[7];
    const float* Wd1 = (const float*)d_in[8];
    const float* bd1 = (const float*)d_in[9];
    const float* Wd2 = (const float*)d_in[10];
    const float* bd2 = (const float*)d_in[11];
    const float* Wd3 = (const float*)d_in[12];
    const float* bd3 = (const float*)d_in[13];
    float* out = (float*)d_out;

    // workspace layout (all 16B aligned)
    char* base = (char*)d_ws;
    int*   deg    = (int*)base;   base += (size_t)n * 4;
    int*   offs   = (int*)base;   base += (size_t)(n + 4) * 4;
    int*   cursor = (int*)base;   base += (size_t)(n + 4) * 4;
    int*   bsum   = (int*)base;   base += (size_t)1024 * 4;
    float* dinv_s = (float*)base; base += (size_t)n * 4;
    float* dinv_h = (float*)base; base += (size_t)n * 4;
    int*   src    = (int*)base;   base += (size_t)E * 4;
    float* swp    = (float*)base; base += (size_t)E * 4;
    float* hwp    = (float*)base; base += (size_t)E * 4;
    float* bufA   = (float*)base; base += (size_t)n * 64 * 4;
    float* bufB   = (float*)base; base += (size_t)n * 64 * 4;
    (void)ws_size;

    const int BLK = 256;
    const int nb = ceil_div(n + 1, SCAN_BLK);   // scan covers [0, n]

    // --- degrees & norms ---
    hipMemsetAsync(deg, 0, (size_t)n * 4, stream);
    deg_kernel<<<ceil_div(E, BLK), BLK, 0, stream>>>(col, deg, E);
    dinv_kernel<<<ceil_div(n, BLK), BLK, 0, stream>>>(deg, dinv_s, dinv_h, n);

    // --- CSR build: scan degrees -> offs[0..n], then permute edges ---
    blk_reduce_kernel<<<nb, SCAN_BLK, 0, stream>>>(deg, bsum, n);
    bsum_scan_kernel<<<1, 1024, 0, stream>>>(bsum, nb);
    offs_kernel<<<nb, SCAN_BLK, 0, stream>>>(deg, bsum, offs, n);
    hipMemcpyAsync(cursor, offs, (size_t)n * 4, hipMemcpyDeviceToDevice, stream);
    csr_fill_kernel<<<ceil_div(E, BLK), BLK, 0, stream>>>(
        row, col, dinv_s, dinv_h, cursor, src, swp, hwp, E);

    auto gemm_grid = [&](int dout) { return ceil_div(n, BLK / dout); };
    auto gath_grid = [&](int dout) { return ceil_div(n * (dout >> 2), BLK); };

    // ================= encoder (smooth): GEMM then propagate =================
    // L1: x(128) @ We1 -> H(64); gather + be1 (relu deferred to consumer)
    gemm_kernel<false, false, false><<<gemm_grid(64), BLK, 128 * 64 * 4, stream>>>(
        x, We1, nullptr, bufA, n, 128, 64);
    gather_kernel<false, true><<<gath_grid(64), BLK, 0, stream>>>(
        bufA, offs, src, swp, dinv_s, 1.0f, be1, bufB, n, 64, dq_shift_of(64));

    // L2: relu(P1)(64) @ We2 -> H(32); gather + be2
    gemm_kernel<true, false, false><<<gemm_grid(32), BLK, 64 * 32 * 4, stream>>>(
        bufB, We2, nullptr, bufA, n, 64, 32);
    gather_kernel<false, true><<<gath_grid(32), BLK, 0, stream>>>(
        bufA, offs, src, swp, dinv_s, 1.0f, be2, bufB, n, 32, dq_shift_of(32));

    // L3: relu(P2)(32) @ We3 -> H(16); gather + be3 -> Z (pre-relu) in bufB
    gemm_kernel<true, false, false><<<gemm_grid(16), BLK, 32 * 16 * 4, stream>>>(
        bufB, We3, nullptr, bufA, n, 32, 16);
    gather_kernel<false, true><<<gath_grid(16), BLK, 0, stream>>>(
        bufA, offs, src, swp, dinv_s, 1.0f, be3, bufB, n, 16, dq_shift_of(16));

    // ================= decoder (sharp): propagate then GEMM =================
    // L4: Q = prop(relu(Z))(16); Q @ Wd1 + bd1, relu
    gather_kernel<true, false><<<gath_grid(16), BLK, 0, stream>>>(
        bufB, offs, src, hwp, dinv_h, 2.0f, nullptr, bufA, n, 16, dq_shift_of(16));
    gemm_kernel<false, true, true><<<gemm_grid(32), BLK, 16 * 32 * 4, stream>>>(
        bufA, Wd1, bd1, bufB, n, 16, 32);

    // L5: Q = prop(h)(32); Q @ Wd2 + bd2, relu
    gather_kernel<false, false><<<gath_grid(32), BLK, 0, stream>>>(
        bufB, offs, src, hwp, dinv_h, 2.0f, nullptr, bufA, n, 32, dq_shift_of(32));
    gemm_kernel<false, true, true><<<gemm_grid(64), BLK, 32 * 64 * 4, stream>>>(
        bufA, Wd2, bd2, bufB, n, 32, 64);

    // L6: Q = prop(h)(64); Q @ Wd3 + bd3 -> d_out (no relu)
    gather_kernel<false, false><<<gath_grid(64), BLK, 0, stream>>>(
        bufB, offs, src, hwp, dinv_h, 2.0f, nullptr, bufA, n, 64, dq_shift_of(64));
    gemm_kernel<false, true, false><<<gemm_grid(128), BLK, 64 * 128 * 4, stream>>>(
        bufA, Wd3, bd3, out, n, 64, 128);
}

// Round 3
// 366.497 us; speedup vs baseline: 6.8396x; 2.6857x over previous
//
#include <hip/hip_runtime.h>

// GALA graph autoencoder on MI355X — round 3: register-blocked GEMM.
// N=100000 nodes, E=600000 edges, dims 128->64->32->16->32->64->128.
// prop(A@W) == prop(A)@W, so propagate at the smaller feature dim.
// Propagation = CSR gather (no float atomics). GEMM = A-tile in LDS,
// 4 rows x 4 cols per thread, W read via L1 (footprint <= 32KB).

static inline int ceil_div(int a, int b) { return (a + b - 1) / b; }

#define SCAN_BLK 256

// ---------------- degree / norm precompute ----------------

__global__ void deg_kernel(const int* __restrict__ col, int* __restrict__ deg, int E) {
    int e = blockIdx.x * blockDim.x + threadIdx.x;
    if (e < E) atomicAdd(&deg[col[e]], 1);
}

__global__ void dinv_kernel(const int* __restrict__ deg, float* __restrict__ dinv_s,
                            float* __restrict__ dinv_h, int n) {
    int i = blockIdx.x * blockDim.x + threadIdx.x;
    if (i < n) {
        float d = (float)deg[i];
        dinv_s[i] = rsqrtf(d + 1.0f);  // smooth: deg = indeg + 1 (self loop w=1)
        dinv_h[i] = rsqrtf(d + 2.0f);  // sharp:  deg = indeg + 2 (self loop w=2)
    }
}

// ---------------- CSR build: block scan of degrees ----------------

__global__ void blk_reduce_kernel(const int* __restrict__ deg, int* __restrict__ bsum, int n) {
    __shared__ int s[SCAN_BLK];
    int i = blockIdx.x * SCAN_BLK + threadIdx.x;
    s[threadIdx.x] = (i < n) ? deg[i] : 0;
    __syncthreads();
    for (int st = SCAN_BLK / 2; st > 0; st >>= 1) {
        if (threadIdx.x < st) s[threadIdx.x] += s[threadIdx.x + st];
        __syncthreads();
    }
    if (threadIdx.x == 0) bsum[blockIdx.x] = s[0];
}

// single block of 1024 threads; nb <= 1024. bsum -> exclusive prefix in place.
__global__ void bsum_scan_kernel(int* bsum, int nb) {
    __shared__ int s[1024];
    int t = threadIdx.x;
    int v0 = (t < nb) ? bsum[t] : 0;
    s[t] = v0;
    __syncthreads();
    for (int st = 1; st < 1024; st <<= 1) {
        int add = (t >= st) ? s[t - st] : 0;
        __syncthreads();
        s[t] += add;
        __syncthreads();
    }
    if (t < nb) bsum[t] = s[t] - v0;  // exclusive
}

// offs[i] = bpre[blk] + exclusive_scan_within_block(deg)[i], covers i in [0, n]
__global__ void offs_kernel(const int* __restrict__ deg, const int* __restrict__ bpre,
                            int* __restrict__ offs, int n) {
    __shared__ int s[SCAN_BLK];
    int i = blockIdx.x * SCAN_BLK + threadIdx.x;
    int t = threadIdx.x;
    int v0 = (i < n) ? deg[i] : 0;
    s[t] = v0;
    __syncthreads();
    for (int st = 1; st < SCAN_BLK; st <<= 1) {
        int add = (t >= st) ? s[t - st] : 0;
        __syncthreads();
        s[t] += add;
        __syncthreads();
    }
    if (i <= n) offs[i] = bpre[blockIdx.x] + s[t] - v0;
}

// permute edges into CSR order keyed by col; store src index + both weight sets
__global__ void csr_fill_kernel(const int* __restrict__ row, const int* __restrict__ col,
                                const float* __restrict__ dinv_s, const float* __restrict__ dinv_h,
                                int* __restrict__ cursor, int* __restrict__ src,
                                float* __restrict__ swp, float* __restrict__ hwp, int E) {
    int e = blockIdx.x * blockDim.x + threadIdx.x;
    if (e >= E) return;
    int r = row[e], c = col[e];
    int p = atomicAdd(&cursor[c], 1);
    src[p] = r;
    swp[p] = dinv_s[r] * dinv_s[c];
    hwp[p] = -dinv_h[r] * dinv_h[c];
}

// ---------------- register-blocked GEMM ----------------
// out[n,DOUT] = f(A[n,DIN]) @ W[DIN,DOUT] (+bias) (relu)
// 256 threads; A-tile (BM rows) staged in LDS (relu fused); each thread owns
// RPT rows x 4 cols. W read as float4 straight from global (L1-resident).

template <int DIN, int DOUT, int RPT, bool RELU_IN, bool ADD_BIAS, bool RELU_OUT>
__global__ __launch_bounds__(256) void gemm_tile(const float* __restrict__ A,
                                                 const float* __restrict__ W,
                                                 const float* __restrict__ bias,
                                                 float* __restrict__ out, int n) {
    constexpr int CG  = DOUT / 4;     // col groups of 4
    constexpr int RPI = 256 / CG;     // rows per "iteration" of threads
    constexpr int BM  = RPI * RPT;    // rows per block
    constexpr int LD  = DIN + 4;      // padded LDS stride (float4-aligned)
    constexpr int Q   = DIN / 4;      // float4 per row
    __shared__ float As[BM * LD];

    const int row0 = blockIdx.x * BM;
    for (int i = threadIdx.x; i < BM * Q; i += 256) {
        int r = i / Q, j = i % Q;
        float4 v = make_float4(0.f, 0.f, 0.f, 0.f);
        if (row0 + r < n) v = *(const float4*)(A + (size_t)(row0 + r) * DIN + j * 4);
        if (RELU_IN) {
            v.x = fmaxf(v.x, 0.f); v.y = fmaxf(v.y, 0.f);
            v.z = fmaxf(v.z, 0.f); v.w = fmaxf(v.w, 0.f);
        }
        *(float4*)(&As[r * LD + j * 4]) = v;
    }
    __syncthreads();

    const int cgid = threadIdx.x % CG;
    const int rsub = threadIdx.x / CG;
    float4 acc[RPT];
#pragma unroll
    for (int rr = 0; rr < RPT; ++rr) acc[rr] = make_float4(0.f, 0.f, 0.f, 0.f);

#pragma unroll 8
    for (int k = 0; k < DIN; ++k) {
        float4 w4 = *(const float4*)(W + k * DOUT + cgid * 4);
#pragma unroll
        for (int rr = 0; rr < RPT; ++rr) {
            float av = As[(rsub * RPT + rr) * LD + k];
            acc[rr].x = fmaf(av, w4.x, acc[rr].x);
            acc[rr].y = fmaf(av, w4.y, acc[rr].y);
            acc[rr].z = fmaf(av, w4.z, acc[rr].z);
            acc[rr].w = fmaf(av, w4.w, acc[rr].w);
        }
    }

    float4 b4 = make_float4(0.f, 0.f, 0.f, 0.f);
    if (ADD_BIAS) b4 = *(const float4*)(bias + cgid * 4);
#pragma unroll
    for (int rr = 0; rr < RPT; ++rr) {
        int row = row0 + rsub * RPT + rr;
        if (row >= n) continue;
        float4 o = acc[rr];
        if (ADD_BIAS) { o.x += b4.x; o.y += b4.y; o.z += b4.z; o.w += b4.w; }
        if (RELU_OUT) {
            o.x = fmaxf(o.x, 0.f); o.y = fmaxf(o.y, 0.f);
            o.z = fmaxf(o.z, 0.f); o.w = fmaxf(o.w, 0.f);
        }
        *(float4*)(out + (size_t)row * DOUT + cgid * 4) = o;
    }
}

// ---------------- propagation: fused CSR gather ----------------
// out[node, d4..d4+3] = selfcoef*dinv[node]^2 * f(h[node]) (+bias)
//                     + sum_e w[e] * f(h[src[e]])

template <bool RELU_IN, bool ADD_BIAS>
__global__ void gather_kernel(const float* __restrict__ h, const int* __restrict__ offs,
                              const int* __restrict__ src, const float* __restrict__ wp,
                              const float* __restrict__ dinv, float selfcoef,
                              const float* __restrict__ bias, float* __restrict__ out,
                              int n, int dout, int dq_shift) {
    int idx = blockIdx.x * blockDim.x + threadIdx.x;
    int dq = 1 << dq_shift;           // dout/4
    int node = idx >> dq_shift;
    if (node >= n) return;
    int d4 = (idx & (dq - 1)) << 2;

    float dv = dinv[node];
    float selfw = selfcoef * dv * dv;
    float4 h4 = *(const float4*)(h + (size_t)node * dout + d4);
    if (RELU_IN) {
        h4.x = fmaxf(h4.x, 0.0f); h4.y = fmaxf(h4.y, 0.0f);
        h4.z = fmaxf(h4.z, 0.0f); h4.w = fmaxf(h4.w, 0.0f);
    }
    float4 acc;
    acc.x = selfw * h4.x; acc.y = selfw * h4.y;
    acc.z = selfw * h4.z; acc.w = selfw * h4.w;
    if (ADD_BIAS) {
        acc.x += bias[d4]; acc.y += bias[d4 + 1];
        acc.z += bias[d4 + 2]; acc.w += bias[d4 + 3];
    }

    int s = offs[node], epos = offs[node + 1];
    for (int e = s; e < epos; ++e) {
        int r = src[e];
        float w = wp[e];
        float4 v = *(const float4*)(h + (size_t)r * dout + d4);
        if (RELU_IN) {
            v.x = fmaxf(v.x, 0.0f); v.y = fmaxf(v.y, 0.0f);
            v.z = fmaxf(v.z, 0.0f); v.w = fmaxf(v.w, 0.0f);
        }
        acc.x = fmaf(w, v.x, acc.x); acc.y = fmaf(w, v.y, acc.y);
        acc.z = fmaf(w, v.z, acc.z); acc.w = fmaf(w, v.w, acc.w);
    }
    *(float4*)(out + (size_t)node * dout + d4) = acc;
}

// ---------------- host orchestration ----------------

static int dq_shift_of(int dout) {
    int dq = dout >> 2, s = 0;
    while ((1 << s) < dq) ++s;
    return s;
}

extern "C" void kernel_launch(void* const* d_in, const int* in_sizes, int n_in,
                              void* d_out, int out_size, void* d_ws, size_t ws_size,
                              hipStream_t stream) {
    const int T = 128;
    const int n = in_sizes[0] / T;        // 100000
    const int E = in_sizes[1] / 2;        // 600000

    const float* x   = (const float*)d_in[0];
    const int* eidx  = (const int*)d_in[1];
    const int* row   = eidx;
    const int* col   = eidx + E;
    const float* We1 = (const float*)d_in[2];
    const float* be1 = (const float*)d_in[3];
    const float* We2 = (const float*)d_in[4];
    const float* be2 = (const float*)d_in[5];
    const float* We3 = (const float*)d_in[6];
    const float* be3 = (const float*)d_in[7];
    const float* Wd1 = (const float*)d_in[8];
    const float* bd1 = (const float*)d_in[9];
    const float* Wd2 = (const float*)d_in[10];
    const float* bd2 = (const float*)d_in[11];
    const float* Wd3 = (const float*)d_in[12];
    const float* bd3 = (const float*)d_in[13];
    float* out = (float*)d_out;

    // workspace layout (all 16B aligned)
    char* base = (char*)d_ws;
    int*   deg    = (int*)base;   base += (size_t)n * 4;
    int*   offs   = (int*)base;   base += (size_t)(n + 4) * 4;
    int*   cursor = (int*)base;   base += (size_t)(n + 4) * 4;
    int*   bsum   = (int*)base;   base += (size_t)1024 * 4;
    float* dinv_s = (float*)base; base += (size_t)n * 4;
    float* dinv_h = (float*)base; base += (size_t)n * 4;
    int*   src    = (int*)base;   base += (size_t)E * 4;
    float* swp    = (float*)base; base += (size_t)E * 4;
    float* hwp    = (float*)base; base += (size_t)E * 4;
    float* bufA   = (float*)base; base += (size_t)n * 64 * 4;
    float* bufB   = (float*)base; base += (size_t)n * 64 * 4;
    (void)ws_size;

    const int BLK = 256;
    const int nb = ceil_div(n + 1, SCAN_BLK);   // scan covers [0, n]

    // --- degrees & norms ---
    hipMemsetAsync(deg, 0, (size_t)n * 4, stream);
    deg_kernel<<<ceil_div(E, BLK), BLK, 0, stream>>>(col, deg, E);
    dinv_kernel<<<ceil_div(n, BLK), BLK, 0, stream>>>(deg, dinv_s, dinv_h, n);

    // --- CSR build: scan degrees -> offs[0..n], then permute edges ---
    blk_reduce_kernel<<<nb, SCAN_BLK, 0, stream>>>(deg, bsum, n);
    bsum_scan_kernel<<<1, 1024, 0, stream>>>(bsum, nb);
    offs_kernel<<<nb, SCAN_BLK, 0, stream>>>(deg, bsum, offs, n);
    hipMemcpyAsync(cursor, offs, (size_t)n * 4, hipMemcpyDeviceToDevice, stream);
    csr_fill_kernel<<<ceil_div(E, BLK), BLK, 0, stream>>>(
        row, col, dinv_s, dinv_h, cursor, src, swp, hwp, E);

    auto gath_grid = [&](int dout) { return ceil_div(n * (dout >> 2), BLK); };

    // ================= encoder (smooth): GEMM then propagate =================
    // L1: x(128) @ We1 -> H(64); gather + be1 (relu deferred to consumer)
    gemm_tile<128, 64, 4, false, false, false><<<ceil_div(n, 64), BLK, 0, stream>>>(
        x, We1, nullptr, bufA, n);
    gather_kernel<false, true><<<gath_grid(64), BLK, 0, stream>>>(
        bufA, offs, src, swp, dinv_s, 1.0f, be1, bufB, n, 64, dq_shift_of(64));

    // L2: relu(P1)(64) @ We2 -> H(32); gather + be2
    gemm_tile<64, 32, 4, true, false, false><<<ceil_div(n, 128), BLK, 0, stream>>>(
        bufB, We2, nullptr, bufA, n);
    gather_kernel<false, true><<<gath_grid(32), BLK, 0, stream>>>(
        bufA, offs, src, swp, dinv_s, 1.0f, be2, bufB, n, 32, dq_shift_of(32));

    // L3: relu(P2)(32) @ We3 -> H(16); gather + be3 -> Z (pre-relu) in bufB
    gemm_tile<32, 16, 4, true, false, false><<<ceil_div(n, 256), BLK, 0, stream>>>(
        bufB, We3, nullptr, bufA, n);
    gather_kernel<false, true><<<gath_grid(16), BLK, 0, stream>>>(
        bufA, offs, src, swp, dinv_s, 1.0f, be3, bufB, n, 16, dq_shift_of(16));

    // ================= decoder (sharp): propagate then GEMM =================
    // L4: Q = prop(relu(Z))(16); Q @ Wd1 + bd1, relu
    gather_kernel<true, false><<<gath_grid(16), BLK, 0, stream>>>(
        bufB, offs, src, hwp, dinv_h, 2.0f, nullptr, bufA, n, 16, dq_shift_of(16));
    gemm_tile<16, 32, 4, false, true, true><<<ceil_div(n, 128), BLK, 0, stream>>>(
        bufA, Wd1, bd1, bufB, n);

    // L5: Q = prop(h)(32); Q @ Wd2 + bd2, relu
    gather_kernel<false, false><<<gath_grid(32), BLK, 0, stream>>>(
        bufB, offs, src, hwp, dinv_h, 2.0f, nullptr, bufA, n, 32, dq_shift_of(32));
    gemm_tile<32, 64, 4, false, true, true><<<ceil_div(n, 64), BLK, 0, stream>>>(
        bufA, Wd2, bd2, bufB, n);

    // L6: Q = prop(h)(64); Q @ Wd3 + bd3 -> d_out (no relu)
    gather_kernel<false, false><<<gath_grid(64), BLK, 0, stream>>>(
        bufB, offs, src, hwp, dinv_h, 2.0f, nullptr, bufA, n, 64, dq_shift_of(64));
    gemm_tile<64, 128, 4, false, true, false><<<ceil_div(n, 32), BLK, 0, stream>>>(
        bufA, Wd3, bd3, out, n);
}